// Round 1
// baseline (452.658 us; speedup 1.0000x reference)
//
#include <hip/hip_runtime.h>
#include <stdint.h>

// MPS classifier forward, MI355X.
// Structure:
//   K1: 127 blocks, basis products T_pq = {C0,dC}_n1 @ {C0,dC}_n2 (bf16, parity layout)
//   K2: (64 pairs+special) x 64 batch; combine T basis with (1,a,b,ab), matmul,
//       normalize, log||raw product|| (telescoped round1+round2 logs)
//   R3..R8: standard pairwise rounds on normalized bf16 matrices + special chain
//   final: logits = s . cls^T + sum(logs)

typedef unsigned short u16;
typedef __attribute__((ext_vector_type(8))) short short8;
typedef __attribute__((ext_vector_type(4))) float f32x4;

#define HP 136  // LDS row stride in bf16 elems: 272 B, 16B-aligned, 2-way-bank-free

__device__ __forceinline__ u16 f2b(float f) {
  uint32_t u = __builtin_bit_cast(uint32_t, f);
  u += 0x7FFFu + ((u >> 16) & 1u);
  return (u16)(u >> 16);
}
__device__ __forceinline__ float b2f(u16 b) {
  uint32_t u = ((uint32_t)b) << 16;
  return __builtin_bit_cast(float, u);
}

struct Acc { f32x4 t[4][4]; };

// C(128x128) = A(row-major LDS [m][k]) @ B(via Bt LDS [n][k]); 4 waves, 64x64 each.
__device__ __forceinline__ void mfma128(const u16* Alds, const u16* Blds, Acc& acc) {
  const int tid = threadIdx.x;
  const int wid = tid >> 6, lane = tid & 63;
  const int wm = (wid >> 1) * 64, wn = (wid & 1) * 64;
  const int l16 = lane & 15, quad = lane >> 4;
#pragma unroll
  for (int tm = 0; tm < 4; tm++)
#pragma unroll
    for (int tn = 0; tn < 4; tn++)
      acc.t[tm][tn] = (f32x4){0.f, 0.f, 0.f, 0.f};
#pragma unroll
  for (int kk = 0; kk < 128; kk += 32) {
    short8 af[4], bf[4];
#pragma unroll
    for (int t = 0; t < 4; t++) {
      af[t] = *(const short8*)(Alds + (wm + t * 16 + l16) * HP + kk + quad * 8);
      bf[t] = *(const short8*)(Blds + (wn + t * 16 + l16) * HP + kk + quad * 8);
    }
#pragma unroll
    for (int tm = 0; tm < 4; tm++)
#pragma unroll
      for (int tn = 0; tn < 4; tn++)
        acc.t[tm][tn] = __builtin_amdgcn_mfma_f32_16x16x32_bf16(
            af[tm], bf[tn], acc.t[tm][tn], 0, 0, 0);
  }
}

__device__ __forceinline__ float acc_sumsq(const Acc& acc) {
  float ss = 0.f;
#pragma unroll
  for (int tm = 0; tm < 4; tm++)
#pragma unroll
    for (int tn = 0; tn < 4; tn++)
#pragma unroll
      for (int i = 0; i < 4; i++) {
        float v = acc.t[tm][tn][i];
        ss += v * v;
      }
  return ss;
}

// D layout (m89): row = quad*4 + reg, col = lane&15 within each 16x16 tile.
__device__ __forceinline__ void store_tile(u16* out, const Acc& acc, float scale,
                                           bool transposed) {
  const int tid = threadIdx.x;
  const int wid = tid >> 6, lane = tid & 63;
  const int wm = (wid >> 1) * 64, wn = (wid & 1) * 64;
  const int l16 = lane & 15, quad = lane >> 4;
#pragma unroll
  for (int tm = 0; tm < 4; tm++)
#pragma unroll
    for (int tn = 0; tn < 4; tn++)
#pragma unroll
      for (int i = 0; i < 4; i++) {
        int r = wm + tm * 16 + quad * 4 + i;
        int c = wn + tn * 16 + l16;
        float v = acc.t[tm][tn][i] * scale;
        out[transposed ? (c * 128 + r) : (r * 128 + c)] = f2b(v);
      }
}

__device__ __forceinline__ float block_sum(float v, float* red) {
#pragma unroll
  for (int off = 32; off > 0; off >>= 1) v += __shfl_down(v, off);
  int wid = threadIdx.x >> 6;
  if ((threadIdx.x & 63) == 0) red[wid] = v;
  __syncthreads();
  if (threadIdx.x == 0) red[0] = red[0] + red[1] + red[2] + red[3];
  __syncthreads();
  float s = red[0];
  __syncthreads();
  return s;
}

// ---------------- K1: basis products ----------------
__global__ __launch_bounds__(256) void k1(const float* __restrict__ cores,
                                          u16* __restrict__ T) {
  __shared__ u16 A0[128 * HP], A1[128 * HP], B0[128 * HP], B1[128 * HP];
  const int j = blockIdx.x;  // 0..126 -> pair (o_{2j+1}, o_{2j+2})
  const int n1 = 2 * j + 1, n2 = 2 * j + 2;
  const float* c1 = cores + (size_t)n1 * 32768;
  const float* c2 = cores + (size_t)n2 * 32768;
  const int tid = threadIdx.x;
#pragma unroll 4
  for (int i = 0; i < 64; i++) {
    int lh = tid + i * 256;  // 0..16383
    int l = lh >> 7, h = lh & 127;
    float a0 = c1[(l * 2 + 0) * 128 + h];
    float a1 = c1[(l * 2 + 1) * 128 + h];
    A0[l * HP + h] = f2b(a0);
    A1[l * HP + h] = f2b(a1 - a0);
    float b0 = c2[(l * 2 + 0) * 128 + h];
    float b1 = c2[(l * 2 + 1) * 128 + h];
    B0[h * HP + l] = f2b(b0);        // B basis stored transposed in LDS
    B1[h * HP + l] = f2b(b1 - b0);
  }
  __syncthreads();
  const bool tr = (j % 2) == 0;  // even index -> consumed as B operand -> store C^T
  u16* Tj = T + (size_t)j * 4 * 16384;
  Acc acc;
  mfma128(A0, B0, acc); store_tile(Tj + 0 * 16384, acc, 1.f, tr);  // T00
  mfma128(A0, B1, acc); store_tile(Tj + 1 * 16384, acc, 1.f, tr);  // T01 (coeff b)
  mfma128(A1, B0, acc); store_tile(Tj + 2 * 16384, acc, 1.f, tr);  // T10 (coeff a)
  mfma128(A1, B1, acc); store_tile(Tj + 3 * 16384, acc, 1.f, tr);  // T11 (coeff ab)
}

// combine 4 basis matrices -> one bf16 matrix in padded LDS (layout preserved)
__device__ __forceinline__ void stage_combine(u16* dst, const u16* Tbase, float a,
                                              float bb) {
  const uint4* t00 = (const uint4*)(Tbase);
  const uint4* t01 = (const uint4*)(Tbase + 16384);
  const uint4* t10 = (const uint4*)(Tbase + 32768);
  const uint4* t11 = (const uint4*)(Tbase + 49152);
  const float ab = a * bb;
  const int tid = threadIdx.x;
#pragma unroll
  for (int i = 0; i < 8; i++) {
    int g8 = tid + i * 256;  // uint4 index (8 bf16 each)
    int r = g8 >> 4, c8 = g8 & 15;
    union { uint4 v; u16 s[8]; } v00, v01, v10, v11, o;
    v00.v = t00[g8]; v01.v = t01[g8]; v10.v = t10[g8]; v11.v = t11[g8];
#pragma unroll
    for (int e = 0; e < 8; e++) {
      float v = b2f(v00.s[e]) + a * b2f(v10.s[e]) + bb * b2f(v01.s[e]) +
                ab * b2f(v11.s[e]);
      o.s[e] = f2b(v);
    }
    *(uint4*)(dst + r * HP + c8 * 8) = o.v;
  }
}

// ---------------- K2: fused rounds 1+2 ----------------
__global__ __launch_bounds__(256) void k2(const float* __restrict__ x,
                                          const float* __restrict__ core0,
                                          const float* __restrict__ cores,
                                          const u16* __restrict__ T,
                                          u16* __restrict__ M0,
                                          float* __restrict__ sA,
                                          float* __restrict__ logs) {
  __shared__ u16 Ald[128 * HP];
  __shared__ u16 Bld[128 * HP];
  __shared__ float red[4];
  const int b = blockIdx.y;
  const int p = blockIdx.x;  // 0 = special chain, 1..63 = pair j2 = p-1
  const int tid = threadIdx.x;
  const float* xb = x + b * 256;

  if (p == 0) {
    float* svec = (float*)Ald;  // 128 floats
    float x0 = xb[0], x1 = xb[1];
    if (tid < 128) {
      float c00 = core0[tid], c01 = core0[128 + tid];
      svec[tid] = c00 * (1.f - x0) + c01 * x0;
    }
    __syncthreads();
    float acc1 = 0.f;
    if (tid < 128) {
      for (int k = 0; k < 128; k++) {
        float m0 = cores[(k * 2 + 0) * 128 + tid];
        float m1 = cores[(k * 2 + 1) * 128 + tid];
        acc1 += svec[k] * (m0 + x1 * (m1 - m0));
      }
    }
    float tot = block_sum((tid < 128) ? acc1 * acc1 : 0.f, red);
    float n1 = fmaxf(sqrtf(tot), 1e-12f);
    float ln = logf(n1);
    if (tid < 128) svec[tid] = acc1 / n1;
    __syncthreads();
    // P0 combo from T[j=0] (stored transposed: flat [h*128+k]); telescoped log.
    float a = xb[2], bb = xb[3], ab = a * bb;
    float acc2 = 0.f;
    if (tid < 128) {
      for (int k8 = 0; k8 < 16; k8++) {
        union { uint4 v; u16 s[8]; } q00, q01, q10, q11;
        q00.v = *(const uint4*)(T + tid * 128 + k8 * 8);
        q01.v = *(const uint4*)(T + 16384 + tid * 128 + k8 * 8);
        q10.v = *(const uint4*)(T + 32768 + tid * 128 + k8 * 8);
        q11.v = *(const uint4*)(T + 49152 + tid * 128 + k8 * 8);
#pragma unroll
        for (int e = 0; e < 8; e++) {
          float pk = b2f(q00.s[e]) + a * b2f(q10.s[e]) + bb * b2f(q01.s[e]) +
                     ab * b2f(q11.s[e]);
          acc2 += svec[k8 * 8 + e] * pk;
        }
      }
    }
    float tot2 = block_sum((tid < 128) ? acc2 * acc2 : 0.f, red);
    float n2 = fmaxf(sqrtf(tot2), 1e-12f);
    if (tid < 128) sA[b * 128 + tid] = acc2 / n2;
    if (tid == 0) logs[b * 127 + 0] = ln + logf(n2);
  } else {
    const int j2 = p - 1;
    const int m1 = 2 * j2 + 1, m2 = 2 * j2 + 2;
    const u16* TA = T + (size_t)m1 * 4 * 16384;  // odd -> row-major
    const u16* TB = T + (size_t)m2 * 4 * 16384;  // even -> transposed
    float a1 = xb[2 * m1 + 2], b1 = xb[2 * m1 + 3];
    float a2 = xb[2 * m2 + 2], b2 = xb[2 * m2 + 3];
    stage_combine(Ald, TA, a1, b1);
    stage_combine(Bld, TB, a2, b2);
    __syncthreads();
    Acc acc;
    mfma128(Ald, Bld, acc);
    float tot = block_sum(acc_sumsq(acc), red);
    float n = fmaxf(sqrtf(tot), 1e-12f);
    if (tid == 0) logs[b * 127 + p] = logf(n);  // = log nA + log nB + log n_round2
    store_tile(M0 + ((size_t)b * 63 + j2) * 16384, acc, 1.f / n, (j2 % 2) == 0);
  }
}

// ---------------- R3..R8: generic pairwise round ----------------
__global__ __launch_bounds__(256) void roundk(const u16* __restrict__ In,
                                              u16* __restrict__ Out,
                                              const float* __restrict__ sIn,
                                              float* __restrict__ sOut,
                                              float* __restrict__ logs,
                                              int count_in, int slot0) {
  __shared__ u16 Ald[128 * HP];
  __shared__ u16 Bld[128 * HP];
  __shared__ float red[4];
  const int b = blockIdx.y;
  const int p = blockIdx.x;
  const int tid = threadIdx.x;

  if (p == 0) {
    float* svec = (float*)Ald;
    if (tid < 128) svec[tid] = sIn[b * 128 + tid];
    __syncthreads();
    const u16* M = In + (size_t)b * count_in * 16384;  // In[b][0], transposed layout
    float acc = 0.f;
    if (tid < 128) {
      for (int k8 = 0; k8 < 16; k8++) {
        union { uint4 v; u16 s[8]; } q;
        q.v = *(const uint4*)(M + tid * 128 + k8 * 8);
#pragma unroll
        for (int e = 0; e < 8; e++) acc += svec[k8 * 8 + e] * b2f(q.s[e]);
      }
    }
    float tot = block_sum((tid < 128) ? acc * acc : 0.f, red);
    float n = fmaxf(sqrtf(tot), 1e-12f);
    if (tid < 128) sOut[b * 128 + tid] = acc / n;
    if (tid == 0) logs[b * 127 + slot0] = logf(n);
  } else {
    const u16* A = In + ((size_t)b * count_in + (2 * p - 1)) * 16384;
    const u16* Bm = In + ((size_t)b * count_in + (2 * p)) * 16384;
#pragma unroll
    for (int i = 0; i < 8; i++) {
      int g8 = tid + i * 256;
      int r = g8 >> 4, c8 = g8 & 15;
      *(uint4*)(Ald + r * HP + c8 * 8) = *(const uint4*)(A + g8 * 8);
      *(uint4*)(Bld + r * HP + c8 * 8) = *(const uint4*)(Bm + g8 * 8);
    }
    __syncthreads();
    Acc acc;
    mfma128(Ald, Bld, acc);
    float tot = block_sum(acc_sumsq(acc), red);
    float n = fmaxf(sqrtf(tot), 1e-12f);
    if (tid == 0) logs[b * 127 + slot0 + p] = logf(n);
    int m = p - 1;
    int count_out = (count_in - 1) / 2;
    store_tile(Out + ((size_t)b * count_out + m) * 16384, acc, 1.f / n, (m % 2) == 0);
  }
}

// ---------------- final: logits ----------------
__global__ __launch_bounds__(128) void finalk(const float* __restrict__ s,
                                              const float* __restrict__ logs,
                                              const float* __restrict__ cls,
                                              float* __restrict__ out) {
  __shared__ float sv[128];
  const int b = blockIdx.x, tid = threadIdx.x;
  sv[tid] = s[b * 128 + tid];
  __syncthreads();
  if (tid < 10) {
    float acc = 0.f;
    for (int h = 0; h < 128; h++) acc += sv[h] * cls[tid * 128 + h];
    float lg = 0.f;
    for (int i = 0; i < 127; i++) lg += logs[b * 127 + i];
    out[b * 10 + tid] = acc + lg;
  }
}

extern "C" void kernel_launch(void* const* d_in, const int* in_sizes, int n_in,
                              void* d_out, int out_size, void* d_ws, size_t ws_size,
                              hipStream_t stream) {
  (void)in_sizes; (void)n_in; (void)out_size; (void)ws_size;
  const float* x     = (const float*)d_in[0];  // (64,256)
  const float* core0 = (const float*)d_in[1];  // (1,2,128)
  const float* cores = (const float*)d_in[2];  // (255,128,2,128)
  const float* cls   = (const float*)d_in[3];  // (10,128)
  float* out = (float*)d_out;
  char* ws = (char*)d_ws;

  constexpr size_t SZ_T  = (size_t)127 * 4 * 16384 * 2;  //  16,646,144
  constexpr size_t SZ_M0 = (size_t)64 * 63 * 16384 * 2;  // 132,120,576
  constexpr size_t SZ_M1 = (size_t)64 * 31 * 16384 * 2;  //  65,011,712
  constexpr size_t SZ_S  = (size_t)64 * 128 * 4;         //      32,768

  u16*   T    = (u16*)(ws);
  u16*   M0   = (u16*)(ws + SZ_T);
  u16*   M1   = (u16*)(ws + SZ_T + SZ_M0);
  float* sA   = (float*)(ws + SZ_T + SZ_M0 + SZ_M1);
  float* sB   = (float*)(ws + SZ_T + SZ_M0 + SZ_M1 + SZ_S);
  float* logs = (float*)(ws + SZ_T + SZ_M0 + SZ_M1 + 2 * SZ_S);

  k1<<<dim3(127), 256, 0, stream>>>(cores, T);
  k2<<<dim3(64, 64), 256, 0, stream>>>(x, core0, cores, T, M0, sA, logs);
  // log slots: K2 0..63, R3 64..95, R4 96..111, R5 112..119, R6 120..123,
  //            R7 124..125, R8 126
  roundk<<<dim3(32, 64), 256, 0, stream>>>(M0, M1, sA, sB, logs, 63, 64);
  roundk<<<dim3(16, 64), 256, 0, stream>>>(M1, M0, sB, sA, logs, 31, 96);
  roundk<<<dim3(8, 64),  256, 0, stream>>>(M0, M1, sA, sB, logs, 15, 112);
  roundk<<<dim3(4, 64),  256, 0, stream>>>(M1, M0, sB, sA, logs, 7, 120);
  roundk<<<dim3(2, 64),  256, 0, stream>>>(M0, M1, sA, sB, logs, 3, 124);
  roundk<<<dim3(1, 64),  256, 0, stream>>>(M1, M0, sB, sA, logs, 1, 126);
  finalk<<<dim3(64), 128, 0, stream>>>(sA, logs, cls, out);
}